// Round 1
// baseline (714.584 us; speedup 1.0000x reference)
//
#include <hip/hip_runtime.h>
#include <math.h>

#define D_MODEL 2048
#define D_STATE 16
#define D_EVENT 32
#define BATCH   2048

typedef __attribute__((ext_vector_type(4))) float f32x4;
typedef __attribute__((ext_vector_type(8))) short short8;
typedef __attribute__((ext_vector_type(8))) __bf16 bf16x8;
typedef __attribute__((ext_vector_type(4))) unsigned short us4;

// fp32 -> bf16 round-to-nearest-even (inputs are well-behaved, no NaN/Inf handling)
__device__ inline unsigned short f2bf(float f) {
  unsigned int u = __builtin_bit_cast(unsigned int, f);
  u += 0x7fffu + ((u >> 16) & 1u);
  return (unsigned short)(u >> 16);
}

// ---------------------------------------------------------------------------
// Kernel 1: bf16 conversions (x, Wd, event, We) + A_base = -exp(clip(A_log,-3,1))
// ---------------------------------------------------------------------------
__global__ __launch_bounds__(256) void prep_kernel(
    const float* __restrict__ x, const float* __restrict__ wd,
    const float* __restrict__ ev, const float* __restrict__ we,
    const float* __restrict__ alog,
    unsigned short* __restrict__ xb, unsigned short* __restrict__ wdb,
    unsigned short* __restrict__ evb, unsigned short* __restrict__ web,
    float* __restrict__ abase)
{
  const int t = blockIdx.x * 256 + threadIdx.x;
  if (t < (BATCH * D_MODEL) / 4) {
    f32x4 v = *(const f32x4*)(x + (size_t)t * 4);
    f32x4 w = *(const f32x4*)(wd + (size_t)t * 4);
    us4 ov, ow;
#pragma unroll
    for (int r = 0; r < 4; ++r) { ov[r] = f2bf(v[r]); ow[r] = f2bf(w[r]); }
    *(us4*)(xb + (size_t)t * 4) = ov;
    *(us4*)(wdb + (size_t)t * 4) = ow;
  }
  if (t < (BATCH * D_EVENT) / 4) {   // == (D_MODEL*D_EVENT)/4
    f32x4 e = *(const f32x4*)(ev + (size_t)t * 4);
    f32x4 s = *(const f32x4*)(we + (size_t)t * 4);
    us4 oe, os;
#pragma unroll
    for (int r = 0; r < 4; ++r) { oe[r] = f2bf(e[r]); os[r] = f2bf(s[r]); }
    *(us4*)(evb + (size_t)t * 4) = oe;
    *(us4*)(web + (size_t)t * 4) = os;
  }
  if (t < (D_MODEL * D_STATE) / 4) {
    f32x4 a = *(const f32x4*)(alog + (size_t)t * 4);
    f32x4 o;
#pragma unroll
    for (int r = 0; r < 4; ++r) {
      float c = fminf(fmaxf(a[r], -3.0f), 1.0f);
      o[r] = -expf(c);
    }
    *(f32x4*)(abase + (size_t)t * 4) = o;
  }
}

// ---------------------------------------------------------------------------
// Kernel 2: per-row B_t = silu(x@B_W1.T + b1)@B_W2.T + b2 + ev@B_We.T ; C_t = x@C_W.T
// one block (4 waves) per batch row; 48 K=2048 dots -> 12 per wave
// ---------------------------------------------------------------------------
__global__ __launch_bounds__(256) void bc_kernel(
    const float* __restrict__ x, const float* __restrict__ ev,
    const float* __restrict__ BW1, const float* __restrict__ Bb1,
    const float* __restrict__ BW2, const float* __restrict__ Bb2,
    const float* __restrict__ BWe, const float* __restrict__ CW,
    float* __restrict__ Bt, float* __restrict__ Ct)
{
  __shared__ float xs[D_MODEL];
  __shared__ float t1s[2 * D_STATE];
  const int b = blockIdx.x, tid = threadIdx.x;
  f32x4* xs4 = (f32x4*)xs;
  const f32x4* xg = (const f32x4*)(x + (size_t)b * D_MODEL);
  xs4[tid] = xg[tid];
  xs4[tid + 256] = xg[tid + 256];
  __syncthreads();
  const int wave = tid >> 6, lane = tid & 63;
#pragma unroll 1
  for (int jj = 0; jj < 12; ++jj) {
    const int j = wave * 12 + jj;
    const float* wr = (j < 32) ? (BW1 + (size_t)j * D_MODEL)
                               : (CW + (size_t)(j - 32) * D_MODEL);
    float s = 0.f;
    for (int k = lane; k < D_MODEL; k += 64) s += xs[k] * wr[k];
#pragma unroll
    for (int o = 32; o > 0; o >>= 1) s += __shfl_xor(s, o);
    if (lane == 0) {
      if (j < 32) {
        float z = s + Bb1[j];
        t1s[j] = z / (1.f + expf(-z));   // silu
      } else {
        Ct[b * D_STATE + (j - 32)] = s;
      }
    }
  }
  __syncthreads();
  if (tid < D_STATE) {
    const int n = tid;
    float s = Bb2[n];
    const float* w2 = BW2 + n * (2 * D_STATE);
    const float* we = BWe + n * D_EVENT;
    const float* eb = ev + (size_t)b * D_EVENT;
#pragma unroll
    for (int k = 0; k < 2 * D_STATE; ++k) s += t1s[k] * w2[k];
#pragma unroll
    for (int k = 0; k < D_EVENT; ++k) s += eb[k] * we[k];
    Bt[b * D_STATE + n] = s;
  }
}

// ---------------------------------------------------------------------------
// Kernel 3: delta_safe = min(softplus(x@Wd.T + bd + ev@We.T), 2)  via bf16 MFMA
// m97 recipe: 128x128 tile, BK=32, global_load_lds width 16, 4 waves x 4x4 accs
// event@We.T folded in as one augmented K-step (K = 2048 + 32)
// ---------------------------------------------------------------------------
__device__ inline void gld_lds16(const unsigned short* g, unsigned short* l) {
  __builtin_amdgcn_global_load_lds(
      (const __attribute__((address_space(1))) unsigned int*)g,
      (__attribute__((address_space(3))) unsigned int*)l, 16, 0, 0);
}

__global__ __launch_bounds__(256) void gemm_delta(
    const unsigned short* __restrict__ xb, const unsigned short* __restrict__ wdb,
    const unsigned short* __restrict__ evb, const unsigned short* __restrict__ web,
    const float* __restrict__ bd, float* __restrict__ delta)
{
  __shared__ unsigned short As[128 * 32];
  __shared__ unsigned short Bs[128 * 32];
  const int tid = threadIdx.x;
  const int wave = tid >> 6, lane = tid & 63;
  const int r16 = lane & 15, q = lane >> 4;
  const int b0 = blockIdx.y * 128, d0 = blockIdx.x * 128;
  const int wm = (wave >> 1) * 64, wn = (wave & 1) * 64;
  const int srow = tid >> 2, skp = tid & 3;  // staging: chunk ch=c*256+tid -> row=ch>>2,kpart=ch&3
  f32x4 acc[4][4] = {};

  for (int kt = 0; kt < D_MODEL / 32; ++kt) {
    const int k0 = kt * 32;
#pragma unroll
    for (int c = 0; c < 2; ++c) {
      // LDS element offset of chunk ch is ch*8 -> wave-uniform base c*2048 + wave*512 (+lane*8 by HW)
      gld_lds16(xb + (size_t)(b0 + srow + c * 64) * D_MODEL + k0 + skp * 8,
                As + c * 2048 + wave * 512);
      gld_lds16(wdb + (size_t)(d0 + srow + c * 64) * D_MODEL + k0 + skp * 8,
                Bs + c * 2048 + wave * 512);
    }
    __syncthreads();
    bf16x8 af[4], bf[4];
#pragma unroll
    for (int i = 0; i < 4; ++i) {
      af[i] = __builtin_bit_cast(bf16x8, *(const short8*)(As + (wm + i * 16 + r16) * 32 + q * 8));
      bf[i] = __builtin_bit_cast(bf16x8, *(const short8*)(Bs + (wn + i * 16 + r16) * 32 + q * 8));
    }
#pragma unroll
    for (int i = 0; i < 4; ++i)
#pragma unroll
      for (int j = 0; j < 4; ++j)
        acc[i][j] = __builtin_amdgcn_mfma_f32_16x16x32_bf16(af[i], bf[j], acc[i][j], 0, 0, 0);
    __syncthreads();
  }
  {  // augmented K-step: + event @ We.T  (K=32)
#pragma unroll
    for (int c = 0; c < 2; ++c) {
      gld_lds16(evb + (size_t)(b0 + srow + c * 64) * D_EVENT + skp * 8,
                As + c * 2048 + wave * 512);
      gld_lds16(web + (size_t)(d0 + srow + c * 64) * D_EVENT + skp * 8,
                Bs + c * 2048 + wave * 512);
    }
    __syncthreads();
    bf16x8 af[4], bf[4];
#pragma unroll
    for (int i = 0; i < 4; ++i) {
      af[i] = __builtin_bit_cast(bf16x8, *(const short8*)(As + (wm + i * 16 + r16) * 32 + q * 8));
      bf[i] = __builtin_bit_cast(bf16x8, *(const short8*)(Bs + (wn + i * 16 + r16) * 32 + q * 8));
    }
#pragma unroll
    for (int i = 0; i < 4; ++i)
#pragma unroll
      for (int j = 0; j < 4; ++j)
        acc[i][j] = __builtin_amdgcn_mfma_f32_16x16x32_bf16(af[i], bf[j], acc[i][j], 0, 0, 0);
  }
  // epilogue: + bd, softplus, clamp at 2.0. C/D layout: row=(lane>>4)*4+reg, col=lane&15
#pragma unroll
  for (int j = 0; j < 4; ++j) {
    const int d = d0 + wn + j * 16 + r16;
    const float bdv = bd[d];
#pragma unroll
    for (int i = 0; i < 4; ++i) {
      const int brow = b0 + wm + i * 16 + q * 4;
#pragma unroll
      for (int r = 0; r < 4; ++r) {
        float pre = acc[i][j][r] + bdv;
        float sp = fmaxf(pre, 0.f) + log1pf(__expf(-fabsf(pre)));
        delta[(size_t)(brow + r) * D_MODEL + d] = fminf(sp, 2.0f);
      }
    }
  }
}

// ---------------------------------------------------------------------------
// Kernel 4: state update + y. 4 lanes per (b,d) pair, 4 states (one float4) per lane.
// A_bar = exp2( delta*log2e * (A_base[d,n] + pole[b,d]) )
// h = A_bar*h_prev + delta*B_t[b,n]*x[b,d] ;  y = sum_n h*C_t[b,n] + D[d]*x[b,d]
// ---------------------------------------------------------------------------
__global__ __launch_bounds__(256) void update_kernel(
    const float* __restrict__ hprev, const float* __restrict__ x,
    const float* __restrict__ ev, const float* __restrict__ AWe,
    const float* __restrict__ Dv,
    const float* __restrict__ delta, const float* __restrict__ abase,
    const float* __restrict__ Bt, const float* __restrict__ Ct,
    float* __restrict__ y, float* __restrict__ h)
{
  const int t = blockIdx.x * 256 + threadIdx.x;
  const int pid = t >> 2, qq = t & 3;
  const int b = pid >> 11, d = pid & (D_MODEL - 1);

  f32x4 hp = *(const f32x4*)(hprev + (size_t)pid * D_STATE + qq * 4);
  f32x4 ab = *(const f32x4*)(abase + d * D_STATE + qq * 4);
  f32x4 bt = *(const f32x4*)(Bt + b * D_STATE + qq * 4);
  f32x4 ct = *(const f32x4*)(Ct + b * D_STATE + qq * 4);
  const float dlt = delta[pid];
  const float xv = x[pid];

  // pole = dot(ev[b,:32], AWe[d,:32]); quad-distributed (8 MACs/lane) + quad reduce
  const float* evp = ev + (size_t)b * D_EVENT + qq * 8;
  const float* awp = AWe + (size_t)d * D_EVENT + qq * 8;
  f32x4 e0 = *(const f32x4*)evp, e1 = *(const f32x4*)(evp + 4);
  f32x4 a0 = *(const f32x4*)awp, a1 = *(const f32x4*)(awp + 4);
  float p = e0[0]*a0[0] + e0[1]*a0[1] + e0[2]*a0[2] + e0[3]*a0[3]
          + e1[0]*a1[0] + e1[1]*a1[1] + e1[2]*a1[2] + e1[3]*a1[3];
  p += __shfl_xor(p, 1);
  p += __shfl_xor(p, 2);

  const float dl2 = dlt * 1.4426950408889634f;  // delta * log2(e)
  const float bx = dlt * xv;
  f32x4 hn;
  float yp = 0.f;
#pragma unroll
  for (int r = 0; r < 4; ++r) {
    float abar = exp2f(dl2 * (ab[r] + p));
    float hv = abar * hp[r] + bx * bt[r];
    hn[r] = hv;
    yp += hv * ct[r];
  }
  *(f32x4*)(h + (size_t)pid * D_STATE + qq * 4) = hn;
  yp += __shfl_xor(yp, 1);
  yp += __shfl_xor(yp, 2);
  if (qq == 0) y[pid] = yp + Dv[d] * xv;
}

// ---------------------------------------------------------------------------
extern "C" void kernel_launch(void* const* d_in, const int* in_sizes, int n_in,
                              void* d_out, int out_size, void* d_ws, size_t ws_size,
                              hipStream_t stream) {
  const float* x     = (const float*)d_in[0];
  const float* hprev = (const float*)d_in[1];
  const float* ev    = (const float*)d_in[2];
  const float* alog  = (const float*)d_in[3];
  const float* Dv    = (const float*)d_in[4];
  const float* Wd    = (const float*)d_in[5];
  const float* bd    = (const float*)d_in[6];
  const float* We    = (const float*)d_in[7];
  const float* BW1   = (const float*)d_in[8];
  const float* Bb1   = (const float*)d_in[9];
  const float* BW2   = (const float*)d_in[10];
  const float* Bb2   = (const float*)d_in[11];
  const float* BWe   = (const float*)d_in[12];
  const float* AWe   = (const float*)d_in[13];
  const float* CW    = (const float*)d_in[14];

  float* y = (float*)d_out;                         // (B, D_MODEL)
  float* h = (float*)d_out + (size_t)BATCH * D_MODEL; // (B, D_MODEL, D_STATE)

  // workspace layout (bytes): ~33.3 MiB total
  char* ws = (char*)d_ws;
  unsigned short* xb  = (unsigned short*)(ws);                      // 8 MiB
  unsigned short* wdb = (unsigned short*)(ws + (8u << 20));         // 8 MiB
  float* delta        = (float*)(ws + (16u << 20));                 // 16 MiB
  float* Bt           = (float*)(ws + (32u << 20));                 // 128 KiB
  float* Ct           = (float*)(ws + (32u << 20) + (128u << 10));  // 128 KiB
  float* abase        = (float*)(ws + (32u << 20) + (256u << 10));  // 128 KiB
  unsigned short* evb = (unsigned short*)(ws + (32u << 20) + (384u << 10)); // 128 KiB
  unsigned short* web = (unsigned short*)(ws + (32u << 20) + (512u << 10)); // 128 KiB

  hipLaunchKernelGGL(prep_kernel, dim3((BATCH * D_MODEL) / 4 / 256), dim3(256), 0, stream,
                     x, Wd, ev, We, alog, xb, wdb, evb, web, abase);
  hipLaunchKernelGGL(bc_kernel, dim3(BATCH), dim3(256), 0, stream,
                     x, ev, BW1, Bb1, BW2, Bb2, BWe, CW, Bt, Ct);
  hipLaunchKernelGGL(gemm_delta, dim3(D_MODEL / 128, BATCH / 128), dim3(256), 0, stream,
                     xb, wdb, evb, web, bd, delta);
  hipLaunchKernelGGL(update_kernel, dim3((size_t)BATCH * D_MODEL * 4 / 256), dim3(256), 0, stream,
                     hprev, x, ev, AWe, Dv, delta, abase, Bt, Ct, y, h);
}